// Round 12
// baseline (83.300 us; speedup 1.0000x reference)
//
#include <hip/hip_runtime.h>
#include <hip/hip_fp16.h>
#include <math.h>

#define N_PIX (256 * 256)
#define N_PTS 192
#define SEGS 8
#define TILE_PIX 64                     // 8x8 pixel tile per block
#define N_BLK (N_PIX / TILE_PIX)        // 1024 blocks
#define THREADS (TILE_PIX * SEGS)       // 512 threads = 8 waves
#define VOL_ELEMS (128 * 128 * 128)     // volq: 8B each = 16 MB

// log2(1 - 1/192); also used for (1 + 1e-10 - 1/192) (diff ~1e-10, negligible)
#define L2Q  (-0.0075336725f)
#define QF   (0.99479166677f)           // 1 + 1e-10 - 1/192

// ---- prep: per voxel pack 4 xy-corners as fp16 into 8B ----
// volq[z][y][x] = { half2(v[z][y][x], v[z][y][x1]), half2(v[z][y1][x], v[z][y1][x1]) }
__global__ __launch_bounds__(256) void pack_kernel(
    const float* __restrict__ vol, uint2* __restrict__ volq)
{
    const int idx = blockIdx.x * 256 + threadIdx.x;   // z*16384 + y*128 + x
    const int x = idx & 127;
    const int y = (idx >> 7) & 127;
    const int z = idx >> 14;
    const int x1 = min(x + 1, 127);
    const int y1 = min(y + 1, 127);
    const float* r0 = vol + (z * 128 + y ) * 128;
    const float* r1 = vol + (z * 128 + y1) * 128;
    const __half2 lo = __floats2half2_rn(r0[x], r0[x1]);
    const __half2 hi = __floats2half2_rn(r1[x], r1[x1]);
    uint2 o;
    o.x = *(const unsigned int*)&lo;
    o.y = *(const unsigned int*)&hi;
    volq[idx] = o;
}

// general (boundary) step: full masks + weight-swap remaps; exact vs reference
__device__ __forceinline__ void general_step(
    const uint2* __restrict__ volq, float pf,
    float A0, float B0, float A1, float B1, float A2, float B2,
    float& S, float& Prun)
{
    const float fx = fmaf(A0, pf, B0);
    const float fy = fmaf(A1, pf, B1);
    const float fz = fmaf(A2, pf, B2);
    const float x0f = floorf(fx), y0f = floorf(fy), z0f = floorf(fz);
    const float wx = fx - x0f, wy = fy - y0f, wz = fz - z0f;
    const int ix = (int)x0f, iy = (int)y0f, iz = (int)z0f;
    const float ax0 = (ix >= 0  && ix <= 127) ? (1.0f - wx) : 0.0f;
    const float ax1 = (ix >= -1 && ix <= 126) ? wx : 0.0f;
    const float ay0 = (iy >= 0  && iy <= 127) ? (1.0f - wy) : 0.0f;
    const float ay1 = (iy >= -1 && iy <= 126) ? wy : 0.0f;
    const float az0 = (iz >= 0  && iz <= 127) ? (1.0f - wz) : 0.0f;
    const float az1 = (iz >= -1 && iz <= 126) ? wz : 0.0f;
    const float s = (ax0 + ax1) * (ay0 + ay1) * (az0 + az1);
    const float dens = s * (1.0f / 192.0f);
    // per-axis edge remap onto the packed base voxel (validated r7/r8)
    int xi = ix; float wx0 = ax0, wx1 = ax1;
    if (xi < 0) { xi = 0; wx0 = ax1; wx1 = 0.0f; } else { xi = min(xi, 127); }
    int yi = iy; float wy0 = ay0, wy1 = ay1;
    if (yi < 0) { yi = 0; wy0 = ay1; wy1 = 0.0f; } else { yi = min(yi, 127); }
    const int zc0 = min(max(iz, 0), 127);
    const int zc1 = min(max(iz + 1, 0), 127);
    const uint2 A = volq[(zc0 * 128 + yi) * 128 + xi];
    const uint2 B = volq[(zc1 * 128 + yi) * 128 + xi];
    const float2 a0 = __half22float2(*(const __half2*)&A.x);
    const float2 a1 = __half22float2(*(const __half2*)&A.y);
    const float2 b0 = __half22float2(*(const __half2*)&B.x);
    const float2 b1 = __half22float2(*(const __half2*)&B.y);
    const float bl0 = wy0 * (wx0 * a0.x + wx1 * a0.y)
                    + wy1 * (wx0 * a1.x + wx1 * a1.y);
    const float bl1 = wy0 * (wx0 * b0.x + wx1 * b0.y)
                    + wy1 * (wx0 * b1.x + wx1 * b1.y);
    const float feat = az0 * bl0 + az1 * bl1;
    S = fmaf(dens * Prun, feat, S);
    Prun *= (1.0f + 1e-10f - dens);
}

__global__ __launch_bounds__(THREADS) void render_kernel(
    const uint2* __restrict__ volq,
    const float* __restrict__ Rm,
    const float* __restrict__ Tv,
    float* __restrict__ out,            // gray image (pre-normalization)
    float* __restrict__ part)           // [4][N_BLK] sum, sq, min, max
{
    const int tid = threadIdx.x;
    const int seg = tid >> 6;           // wave index = depth segment
    const int l   = tid & 63;           // lane = pixel within 8x8 tile
    const int tr  = blockIdx.x >> 5;    // 32x32 grid of 8x8 tiles
    const int tc  = blockIdx.x & 31;
    const int h = tr * 8 + (l >> 3);
    const int w = tc * 8 + (l & 7);
    const float yg = 1.0f - (2.0f / 255.0f) * (float)h;
    const float xg = 1.0f - (2.0f / 255.0f) * (float)w;

    const float r00 = Rm[0], r01 = Rm[1], r02 = Rm[2];
    const float r10 = Rm[3], r11 = Rm[4], r12 = Rm[5];
    const float r20 = Rm[6], r21 = Rm[7], r22 = Rm[8];
    const float t0 = Tv[0], t1 = Tv[1], t2 = Tv[2];

    // world_i(d) = a_i * d + b_i  (linear in depth d)
    const float a0 = 0.25f * (r00 * xg + r01 * yg) + r02;
    const float a1 = 0.25f * (r10 * xg + r11 * yg) + r12;
    const float a2 = 0.25f * (r20 * xg + r21 * yg) + r22;
    const float b0 = -(r00 * t0 + r01 * t1 + r02 * t2);
    const float b1 = -(r10 * t0 + r11 * t1 + r12 * t2);
    const float b2 = -(r20 * t0 + r21 * t1 + r22 * t2);

    const float step = 6.0f / 191.0f;
    const float rstep = 191.0f / 6.0f;

    // voxel coords as linear fn of sample index p: f_i(p) = A_i*p + B_i
    const float A0 = a0 * step * 63.5f, B0 = (fmaf(a0, 3.0f, b0) + 1.0f) * 63.5f;
    const float A1 = a1 * step * 63.5f, B1 = (fmaf(a1, 3.0f, b1) + 1.0f) * 63.5f;
    const float A2 = a2 * step * 63.5f, B2 = (fmaf(a2, 3.0f, b2) + 1.0f) * 63.5f;

    // ---- outer valid interval: any corner in-bounds: |a*d+b| < 1 + 2/127 ----
    const float LIM = 1.0f + 2.0f / 127.0f + 1e-4f;
    // ---- interior interval: all weights valid & s==1: a*d+b in [-1, 1) ----
    const float WHI = 1.0f - 1e-5f;
    float dlo = 3.0f, dhi = 9.0f;       // outer, in d-units
    float dloI = 3.0f, dhiI = 9.0f;     // interior
    {
        const float aa[3] = {a0, a1, a2};
        const float bb[3] = {b0, b1, b2};
        #pragma unroll
        for (int k = 0; k < 3; ++k) {
            const float a = aa[k], b = bb[k];
            if (fabsf(a) > 1e-12f) {
                const float ra = 1.0f / a;
                const float o0 = (-LIM - b) * ra, o1 = (LIM - b) * ra;
                dlo = fmaxf(dlo, fminf(o0, o1));
                dhi = fminf(dhi, fmaxf(o0, o1));
                const float i0 = (-1.0f - b) * ra, i1 = (WHI - b) * ra;
                dloI = fmaxf(dloI, fminf(i0, i1));
                dhiI = fminf(dhiI, fmaxf(i0, i1));
            } else {
                if (fabsf(b) >= LIM) dhi = -1e30f;
                if (b < -1.0f || b > WHI) dhiI = -1e30f;
            }
        }
    }
    int plo = (int)ceilf((dlo - 3.0f) * rstep - 1e-3f);
    int phi = (int)floorf((dhi - 3.0f) * rstep + 1e-3f);
    plo = max(plo, 0);
    phi = min(phi, N_PTS - 1);
    int len = phi - plo + 1;
    if (len < 0) { len = 0; phi = plo - 1; }
    // interior clipped; safety margins push uncertain samples to general path
    int plo2 = (int)ceilf((dloI - 3.0f) * rstep + 1e-3f);
    int phi2 = (int)floorf((dhiI - 3.0f) * rstep - 1e-3f);
    plo2 = max(plo2, plo);
    phi2 = min(phi2, phi);
    if (plo2 > phi2) { plo2 = phi + 1; phi2 = phi; }   // no interior

    const int chunk = (len + SEGS - 1) >> 3;
    const int beg = plo + seg * chunk;
    const int end = min(beg + chunk, plo + len);

    float Prun = 1.0f;  // product of (1+1e-10 - dens) within my chunk
    float S = 0.0f;     // sum dens * local_absorption * feat within my chunk

    // --- boundary prefix (general path) ---
    const int aEnd = min(end, plo2);
    for (int p = beg; p < aEnd; ++p)
        general_step(volq, (float)p, A0, B0, A1, B1, A2, B2, S, Prun);

    // --- interior: s==1, dens==1/192 constant, 2 x 8B unclamped loads ---
    const int i0b = max(beg, plo2);
    const int i1b = min(end, phi2 + 1);
    float qp = 1.0f, S2 = 0.0f;
    #pragma unroll 4
    for (int p = i0b; p < i1b; ++p) {
        const float pf = (float)p;
        const float fx = fmaf(A0, pf, B0);
        const float fy = fmaf(A1, pf, B1);
        const float fz = fmaf(A2, pf, B2);
        const float x0f = floorf(fx), y0f = floorf(fy), z0f = floorf(fz);
        const float wx = fx - x0f, wy = fy - y0f, wz = fz - z0f;
        const int ix = (int)x0f, iy = (int)y0f, iz = (int)z0f;
        const int base = (iz * 128 + iy) * 128 + ix;
        const uint2 A = volq[base];           // z0: (y,x),(y,x1),(y1,x),(y1,x1)
        const uint2 B = volq[base + 16384];   // z1
        const float2 a0v = __half22float2(*(const __half2*)&A.x);
        const float2 a1v = __half22float2(*(const __half2*)&A.y);
        const float2 b0v = __half22float2(*(const __half2*)&B.x);
        const float2 b1v = __half22float2(*(const __half2*)&B.y);
        const float x00 = fmaf(wx, a0v.y - a0v.x, a0v.x);
        const float x01 = fmaf(wx, a1v.y - a1v.x, a1v.x);
        const float x10 = fmaf(wx, b0v.y - b0v.x, b0v.x);
        const float x11 = fmaf(wx, b1v.y - b1v.x, b1v.x);
        const float y0v = fmaf(wy, x01 - x00, x00);
        const float y1v = fmaf(wy, x11 - x10, x10);
        const float feat = fmaf(wz, y1v - y0v, y0v);
        S2 = fmaf(qp, feat, S2);
        qp *= QF;
    }
    if (i1b > i0b) {
        const int kint = i1b - i0b;
        S = fmaf(Prun * (1.0f / 192.0f), S2, S);
        Prun *= exp2f((float)kint * L2Q);
    }

    // --- boundary suffix (general path) ---
    const int bBeg = max(beg, phi2 + 1);
    for (int p = bBeg; p < end; ++p)
        general_step(volq, (float)p, A0, B0, A1, B1, A2, B2, S, Prun);

    // ---- per-(seg,pixel) partials to LDS; wave 0 combines sequentially ----
    __shared__ float sP[SEGS][TILE_PIX];
    __shared__ float sS[SEGS][TILE_PIX];
    sP[seg][l] = Prun;
    sS[seg][l] = S;
    __syncthreads();

    if (tid < TILE_PIX) {
        float absorb = 1.0f, wS = 0.0f;
        #pragma unroll
        for (int s = 0; s < SEGS; ++s) {
            wS = fmaf(absorb, sS[s][l], wS);
            absorb *= sP[s][l];
        }
        // opacity from absorb: prod(1-dens) vs prod(1+1e-10-dens) differ <2e-8
        const float g = (3.0f * wS + (1.0f - absorb)) * 0.25f;
        out[h * 256 + w] = g;

        // wave-0 stats reduction over the 64 tile pixels
        float vs = g, vq = g * g, vmn = g, vmx = g;
        #pragma unroll
        for (int off = 1; off < 64; off <<= 1) {
            vs += __shfl_xor(vs, off);
            vq += __shfl_xor(vq, off);
            vmn = fminf(vmn, __shfl_xor(vmn, off));
            vmx = fmaxf(vmx, __shfl_xor(vmx, off));
        }
        if (l == 0) {
            part[blockIdx.x]             = vs;
            part[N_BLK + blockIdx.x]     = vq;
            part[2 * N_BLK + blockIdx.x] = vmn;
            part[3 * N_BLK + blockIdx.x] = vmx;
        }
    }
}

// Every block redundantly reduces the 1024 partials (L2/L3-hot),
// then normalizes its own 256 pixels. No cross-block ordering needed.
__global__ __launch_bounds__(256) void finish_kernel(
    float* __restrict__ out,
    const float* __restrict__ part)
{
    const int tid = threadIdx.x;
    __shared__ float s_s[4], s_q[4], s_n[4], s_x[4];
    __shared__ float s_fin[4];

    float fs  = part[tid]               + part[tid + 256]
              + part[tid + 512]         + part[tid + 768];
    float fq  = part[N_BLK + tid]       + part[N_BLK + tid + 256]
              + part[N_BLK + tid + 512] + part[N_BLK + tid + 768];
    float fn  = fminf(fminf(part[2 * N_BLK + tid],       part[2 * N_BLK + tid + 256]),
                      fminf(part[2 * N_BLK + tid + 512], part[2 * N_BLK + tid + 768]));
    float fx2 = fmaxf(fmaxf(part[3 * N_BLK + tid],       part[3 * N_BLK + tid + 256]),
                      fmaxf(part[3 * N_BLK + tid + 512], part[3 * N_BLK + tid + 768]));
    #pragma unroll
    for (int off = 1; off < 64; off <<= 1) {
        fs += __shfl_xor(fs, off);
        fq += __shfl_xor(fq, off);
        fn  = fminf(fn,  __shfl_xor(fn, off));
        fx2 = fmaxf(fx2, __shfl_xor(fx2, off));
    }
    const int wave = tid >> 6;
    const int lane = tid & 63;
    if (lane == 0) { s_s[wave] = fs; s_q[wave] = fq; s_n[wave] = fn; s_x[wave] = fx2; }
    __syncthreads();
    if (tid == 0) {
        const float tsum = s_s[0] + s_s[1] + s_s[2] + s_s[3];
        const float tsq  = s_q[0] + s_q[1] + s_q[2] + s_q[3];
        const float tmn  = fminf(fminf(s_n[0], s_n[1]), fminf(s_n[2], s_n[3]));
        const float tmx  = fmaxf(fmaxf(s_x[0], s_x[1]), fmaxf(s_x[2], s_x[3]));
        const float N = (float)N_PIX;
        const float mean = tsum / N;
        float var = (tsq - N * mean * mean) / (N - 1.0f);
        if (var < 0.0f) var = 0.0f;
        const float denom = sqrtf(var) + 1e-8f;
        s_fin[0] = mean;
        s_fin[1] = denom;
        s_fin[2] = (tmn - mean) / denom;   // std.min
        s_fin[3] = (tmx - mean) / denom;   // std.max
    }
    __syncthreads();

    const float mean = s_fin[0];
    const float rdenom = 1.0f / s_fin[1];
    const float smin = s_fin[2];
    const float rrange = 1.0f / (s_fin[3] - smin + 1e-8f);
    const int i = blockIdx.x * 256 + tid;
    const float sv = (out[i] - mean) * rdenom;
    out[i] = (sv - smin + 1e-8f) * rrange;
}

extern "C" void kernel_launch(void* const* d_in, const int* in_sizes, int n_in,
                              void* d_out, int out_size, void* d_ws, size_t ws_size,
                              hipStream_t stream)
{
    const float* vol = (const float*)d_in[0];
    const float* Rm  = (const float*)d_in[1];
    const float* Tv  = (const float*)d_in[2];
    float* out = (float*)d_out;
    uint2* volq = (uint2*)d_ws;                             // 16 MB
    float* part = (float*)((char*)d_ws + VOL_ELEMS * 8);    // 16 KB after volq

    hipLaunchKernelGGL(pack_kernel, dim3(VOL_ELEMS / 256), dim3(256), 0, stream,
                       vol, volq);
    hipLaunchKernelGGL(render_kernel, dim3(N_BLK), dim3(THREADS), 0, stream,
                       volq, Rm, Tv, out, part);
    hipLaunchKernelGGL(finish_kernel, dim3(N_PIX / 256), dim3(256), 0, stream,
                       out, part);
}

// Round 13
// 79.805 us; speedup vs baseline: 1.0438x; 1.0438x over previous
//
#include <hip/hip_runtime.h>
#include <math.h>

#define N_PIX (256 * 256)
#define N_PTS 192
#define SEGS 8
#define TILE_PIX 64                     // 32x2 pixel tile per block
#define N_BLK (N_PIX / TILE_PIX)        // 1024 blocks
#define THREADS (TILE_PIX * SEGS)       // 512 threads = 8 waves

// log2(1 - 1/192); also used for (1 + 1e-10 - 1/192) (diff ~1e-10, negligible)
#define L2Q  (-0.0075336725f)
#define QF   (0.99479166677f)           // 1 + 1e-10 - 1/192

// general (boundary) step: full masks + clamped loads; exact vs reference
__device__ __forceinline__ void general_step(
    const float* __restrict__ vol, float pf,
    float A0, float B0, float A1, float B1, float A2, float B2,
    float& S, float& Prun)
{
    const float fx = fmaf(A0, pf, B0);
    const float fy = fmaf(A1, pf, B1);
    const float fz = fmaf(A2, pf, B2);
    const float x0f = floorf(fx), y0f = floorf(fy), z0f = floorf(fz);
    const float wx = fx - x0f, wy = fy - y0f, wz = fz - z0f;
    const int ix = (int)x0f, iy = (int)y0f, iz = (int)z0f;
    const float ax0 = (ix >= 0  && ix <= 127) ? (1.0f - wx) : 0.0f;
    const float ax1 = (ix >= -1 && ix <= 126) ? wx : 0.0f;
    const float ay0 = (iy >= 0  && iy <= 127) ? (1.0f - wy) : 0.0f;
    const float ay1 = (iy >= -1 && iy <= 126) ? wy : 0.0f;
    const float az0 = (iz >= 0  && iz <= 127) ? (1.0f - wz) : 0.0f;
    const float az1 = (iz >= -1 && iz <= 126) ? wz : 0.0f;
    const float s = (ax0 + ax1) * (ay0 + ay1) * (az0 + az1);
    const float dens = s * (1.0f / 192.0f);
    const int xc0 = min(max(ix, 0), 127), xc1 = min(max(ix + 1, 0), 127);
    const int yc0 = min(max(iy, 0), 127), yc1 = min(max(iy + 1, 0), 127);
    const int zc0 = min(max(iz, 0), 127), zc1 = min(max(iz + 1, 0), 127);
    const float* q00 = vol + (zc0 * 128 + yc0) * 128;
    const float* q01 = vol + (zc0 * 128 + yc1) * 128;
    const float* q10 = vol + (zc1 * 128 + yc0) * 128;
    const float* q11 = vol + (zc1 * 128 + yc1) * 128;
    const float feat =
        az0 * (ay0 * (ax0 * q00[xc0] + ax1 * q00[xc1]) +
               ay1 * (ax0 * q01[xc0] + ax1 * q01[xc1])) +
        az1 * (ay0 * (ax0 * q10[xc0] + ax1 * q10[xc1]) +
               ay1 * (ax0 * q11[xc0] + ax1 * q11[xc1]));
    S = fmaf(dens * Prun, feat, S);
    Prun *= (1.0f + 1e-10f - dens);
}

__global__ __launch_bounds__(THREADS) void render_kernel(
    const float* __restrict__ vol,
    const float* __restrict__ Rm,
    const float* __restrict__ Tv,
    float* __restrict__ out,            // gray image (pre-normalization)
    float* __restrict__ part)           // [4][N_BLK] sum, sq, min, max
{
    const int tid = threadIdx.x;
    const int seg = tid >> 6;           // wave index = depth segment
    const int l   = tid & 63;           // lane = pixel within 32x2 tile
    const int tc  = blockIdx.x & 7;     // 8 tiles across (32 px each)
    const int tr  = blockIdx.x >> 3;    // 128 tile rows (2 px each)
    const int w = tc * 32 + (l & 31);   // 32 consecutive x-pixels per wave row
    const int h = tr * 2 + (l >> 5);
    const float yg = 1.0f - (2.0f / 255.0f) * (float)h;
    const float xg = 1.0f - (2.0f / 255.0f) * (float)w;

    const float r00 = Rm[0], r01 = Rm[1], r02 = Rm[2];
    const float r10 = Rm[3], r11 = Rm[4], r12 = Rm[5];
    const float r20 = Rm[6], r21 = Rm[7], r22 = Rm[8];
    const float t0 = Tv[0], t1 = Tv[1], t2 = Tv[2];

    // world_i(d) = a_i * d + b_i  (linear in depth d)
    const float a0 = 0.25f * (r00 * xg + r01 * yg) + r02;
    const float a1 = 0.25f * (r10 * xg + r11 * yg) + r12;
    const float a2 = 0.25f * (r20 * xg + r21 * yg) + r22;
    const float b0 = -(r00 * t0 + r01 * t1 + r02 * t2);
    const float b1 = -(r10 * t0 + r11 * t1 + r12 * t2);
    const float b2 = -(r20 * t0 + r21 * t1 + r22 * t2);

    const float step = 6.0f / 191.0f;
    const float rstep = 191.0f / 6.0f;

    // voxel coords as linear fn of sample index p: f_i(p) = A_i*p + B_i
    const float A0 = a0 * step * 63.5f, B0 = (fmaf(a0, 3.0f, b0) + 1.0f) * 63.5f;
    const float A1 = a1 * step * 63.5f, B1 = (fmaf(a1, 3.0f, b1) + 1.0f) * 63.5f;
    const float A2 = a2 * step * 63.5f, B2 = (fmaf(a2, 3.0f, b2) + 1.0f) * 63.5f;

    // ---- outer valid interval: any corner in-bounds: |a*d+b| < 1 + 2/127 ----
    const float LIM = 1.0f + 2.0f / 127.0f + 1e-4f;
    // ---- interior interval: all weights valid & s==1: a*d+b in [-1, 1) ----
    const float WHI = 1.0f - 1e-5f;
    float dlo = 3.0f, dhi = 9.0f;       // outer, in d-units
    float dloI = 3.0f, dhiI = 9.0f;     // interior
    {
        const float aa[3] = {a0, a1, a2};
        const float bb[3] = {b0, b1, b2};
        #pragma unroll
        for (int k = 0; k < 3; ++k) {
            const float a = aa[k], b = bb[k];
            if (fabsf(a) > 1e-12f) {
                const float ra = 1.0f / a;
                const float o0 = (-LIM - b) * ra, o1 = (LIM - b) * ra;
                dlo = fmaxf(dlo, fminf(o0, o1));
                dhi = fminf(dhi, fmaxf(o0, o1));
                const float i0 = (-1.0f - b) * ra, i1 = (WHI - b) * ra;
                dloI = fmaxf(dloI, fminf(i0, i1));
                dhiI = fminf(dhiI, fmaxf(i0, i1));
            } else {
                if (fabsf(b) >= LIM) dhi = -1e30f;
                if (b < -1.0f || b > WHI) dhiI = -1e30f;
            }
        }
    }
    int plo = (int)ceilf((dlo - 3.0f) * rstep - 1e-3f);
    int phi = (int)floorf((dhi - 3.0f) * rstep + 1e-3f);
    plo = max(plo, 0);
    phi = min(phi, N_PTS - 1);
    int len = phi - plo + 1;
    if (len < 0) { len = 0; phi = plo - 1; }
    // interior clipped; safety margins push uncertain samples to general path
    int plo2 = (int)ceilf((dloI - 3.0f) * rstep + 1e-3f);
    int phi2 = (int)floorf((dhiI - 3.0f) * rstep - 1e-3f);
    plo2 = max(plo2, plo);
    phi2 = min(phi2, phi);
    if (plo2 > phi2) { plo2 = phi + 1; phi2 = phi; }   // no interior

    const int chunk = (len + SEGS - 1) >> 3;
    const int beg = plo + seg * chunk;
    const int end = min(beg + chunk, plo + len);

    float Prun = 1.0f;  // product of (1+1e-10 - dens) within my chunk
    float S = 0.0f;     // sum dens * local_absorption * feat within my chunk

    // --- boundary prefix (general path) ---
    const int aEnd = min(end, plo2);
    for (int p = beg; p < aEnd; ++p)
        general_step(vol, (float)p, A0, B0, A1, B1, A2, B2, S, Prun);

    // --- interior: s==1, dens==1/192 constant, unclamped loads ---
    const int i0b = max(beg, plo2);
    const int i1b = min(end, phi2 + 1);
    float qp = 1.0f, S2 = 0.0f;
    #pragma unroll 4
    for (int p = i0b; p < i1b; ++p) {
        const float pf = (float)p;
        const float fx = fmaf(A0, pf, B0);
        const float fy = fmaf(A1, pf, B1);
        const float fz = fmaf(A2, pf, B2);
        const float x0f = floorf(fx), y0f = floorf(fy), z0f = floorf(fz);
        const float wx = fx - x0f, wy = fy - y0f, wz = fz - z0f;
        const int ix = (int)x0f, iy = (int)y0f, iz = (int)z0f;
        const float* q0 = vol + ((iz * 128 + iy) * 128 + ix);
        const float v000 = q0[0],     v001 = q0[1];
        const float v010 = q0[128],   v011 = q0[129];
        const float v100 = q0[16384], v101 = q0[16385];
        const float v110 = q0[16512], v111 = q0[16513];
        const float x00 = fmaf(wx, v001 - v000, v000);
        const float x01 = fmaf(wx, v011 - v010, v010);
        const float x10 = fmaf(wx, v101 - v100, v100);
        const float x11 = fmaf(wx, v111 - v110, v110);
        const float y0v = fmaf(wy, x01 - x00, x00);
        const float y1v = fmaf(wy, x11 - x10, x10);
        const float feat = fmaf(wz, y1v - y0v, y0v);
        S2 = fmaf(qp, feat, S2);
        qp *= QF;
    }
    if (i1b > i0b) {
        const int kint = i1b - i0b;
        S = fmaf(Prun * (1.0f / 192.0f), S2, S);
        Prun *= exp2f((float)kint * L2Q);
    }

    // --- boundary suffix (general path) ---
    const int bBeg = max(beg, phi2 + 1);
    for (int p = bBeg; p < end; ++p)
        general_step(vol, (float)p, A0, B0, A1, B1, A2, B2, S, Prun);

    // ---- per-(seg,pixel) partials to LDS; wave 0 combines sequentially ----
    __shared__ float sP[SEGS][TILE_PIX];
    __shared__ float sS[SEGS][TILE_PIX];
    sP[seg][l] = Prun;
    sS[seg][l] = S;
    __syncthreads();

    if (tid < TILE_PIX) {
        float absorb = 1.0f, wS = 0.0f;
        #pragma unroll
        for (int s = 0; s < SEGS; ++s) {
            wS = fmaf(absorb, sS[s][l], wS);
            absorb *= sP[s][l];
        }
        // opacity from absorb: prod(1-dens) vs prod(1+1e-10-dens) differ <2e-8
        const float g = (3.0f * wS + (1.0f - absorb)) * 0.25f;
        out[h * 256 + w] = g;

        // wave-0 stats reduction over the 64 tile pixels
        float vs = g, vq = g * g, vmn = g, vmx = g;
        #pragma unroll
        for (int off = 1; off < 64; off <<= 1) {
            vs += __shfl_xor(vs, off);
            vq += __shfl_xor(vq, off);
            vmn = fminf(vmn, __shfl_xor(vmn, off));
            vmx = fmaxf(vmx, __shfl_xor(vmx, off));
        }
        if (l == 0) {
            part[blockIdx.x]             = vs;
            part[N_BLK + blockIdx.x]     = vq;
            part[2 * N_BLK + blockIdx.x] = vmn;
            part[3 * N_BLK + blockIdx.x] = vmx;
        }
    }
}

// Every block redundantly reduces the 1024 partials (L2/L3-hot),
// then normalizes its own 256 pixels. No cross-block ordering needed.
__global__ __launch_bounds__(256) void finish_kernel(
    float* __restrict__ out,
    const float* __restrict__ part)
{
    const int tid = threadIdx.x;
    __shared__ float s_s[4], s_q[4], s_n[4], s_x[4];
    __shared__ float s_fin[4];

    float fs  = part[tid]               + part[tid + 256]
              + part[tid + 512]         + part[tid + 768];
    float fq  = part[N_BLK + tid]       + part[N_BLK + tid + 256]
              + part[N_BLK + tid + 512] + part[N_BLK + tid + 768];
    float fn  = fminf(fminf(part[2 * N_BLK + tid],       part[2 * N_BLK + tid + 256]),
                      fminf(part[2 * N_BLK + tid + 512], part[2 * N_BLK + tid + 768]));
    float fx2 = fmaxf(fmaxf(part[3 * N_BLK + tid],       part[3 * N_BLK + tid + 256]),
                      fmaxf(part[3 * N_BLK + tid + 512], part[3 * N_BLK + tid + 768]));
    #pragma unroll
    for (int off = 1; off < 64; off <<= 1) {
        fs += __shfl_xor(fs, off);
        fq += __shfl_xor(fq, off);
        fn  = fminf(fn,  __shfl_xor(fn, off));
        fx2 = fmaxf(fx2, __shfl_xor(fx2, off));
    }
    const int wave = tid >> 6;
    const int lane = tid & 63;
    if (lane == 0) { s_s[wave] = fs; s_q[wave] = fq; s_n[wave] = fn; s_x[wave] = fx2; }
    __syncthreads();
    if (tid == 0) {
        const float tsum = s_s[0] + s_s[1] + s_s[2] + s_s[3];
        const float tsq  = s_q[0] + s_q[1] + s_q[2] + s_q[3];
        const float tmn  = fminf(fminf(s_n[0], s_n[1]), fminf(s_n[2], s_n[3]));
        const float tmx  = fmaxf(fmaxf(s_x[0], s_x[1]), fmaxf(s_x[2], s_x[3]));
        const float N = (float)N_PIX;
        const float mean = tsum / N;
        float var = (tsq - N * mean * mean) / (N - 1.0f);
        if (var < 0.0f) var = 0.0f;
        const float denom = sqrtf(var) + 1e-8f;
        s_fin[0] = mean;
        s_fin[1] = denom;
        s_fin[2] = (tmn - mean) / denom;   // std.min
        s_fin[3] = (tmx - mean) / denom;   // std.max
    }
    __syncthreads();

    const float mean = s_fin[0];
    const float rdenom = 1.0f / s_fin[1];
    const float smin = s_fin[2];
    const float rrange = 1.0f / (s_fin[3] - smin + 1e-8f);
    const int i = blockIdx.x * 256 + tid;
    const float sv = (out[i] - mean) * rdenom;
    out[i] = (sv - smin + 1e-8f) * rrange;
}

extern "C" void kernel_launch(void* const* d_in, const int* in_sizes, int n_in,
                              void* d_out, int out_size, void* d_ws, size_t ws_size,
                              hipStream_t stream)
{
    const float* vol = (const float*)d_in[0];
    const float* Rm  = (const float*)d_in[1];
    const float* Tv  = (const float*)d_in[2];
    float* out = (float*)d_out;
    float* part = (float*)d_ws;   // 4 * N_BLK floats = 16 KB

    hipLaunchKernelGGL(render_kernel, dim3(N_BLK), dim3(THREADS), 0, stream,
                       vol, Rm, Tv, out, part);
    hipLaunchKernelGGL(finish_kernel, dim3(N_PIX / 256), dim3(256), 0, stream,
                       out, part);
}